// Round 3
// baseline (34.715 us; speedup 1.0000x reference)
//
#include <hip/hip_runtime.h>
#include <cfloat>
#include <climits>

#define B_   8
#define N1_  1024
#define N2_  4096
#define C_   256
#define TPQ  16                 // threads per query
#define QPB  (256 / TPQ)        // 16 queries per block

typedef float vf2 __attribute__((ext_vector_type(2)));

// ---------------------------------------------------------------------------
// Kernel 1: 3-NN search. 16 threads/query, 16 queries/block, 2048 blocks.
// Distances for 2 candidates at a time via packed fp32 (v_pk_mul/add_f32),
// contract(off) so no FMA fusion -> bit-identical to reference:
//   d2 = (|p2|^2 - 2*dot) + |p1|^2, left-to-right (2*dot via pre-doubled
//   coords, exact under RN).
// LDS layout pair-interleaved so packed operands load with no repack moves:
//   Q[k] = {2x[2k], 2x[2k+1], 2y[2k], 2y[2k+1]}
//   R[k] = {2z[2k], 2z[2k+1], s1[2k], s1[2k+1]}
// ---------------------------------------------------------------------------

// Branchless lexicographic insert of (pd,pi) into sorted triple (merge phase).
__device__ __forceinline__ void ins_lex_(float pd, int pi,
                                         float& d0, float& d1, float& d2,
                                         int& i0, int& i1, int& i2) {
    bool l0 = (pd < d0) || (pd == d0 && pi < i0);
    bool l1 = (pd < d1) || (pd == d1 && pi < i1);
    bool l2 = (pd < d2) || (pd == d2 && pi < i2);
    float e0 = l0 ? pd : d0;
    float e1 = l1 ? (l0 ? d0 : pd) : d1;
    float e2 = l2 ? (l1 ? d1 : pd) : d2;
    int   f0 = l0 ? pi : i0;
    int   f1 = l1 ? (l0 ? i0 : pi) : i1;
    int   f2 = l2 ? (l1 ? i1 : pi) : i2;
    d0 = e0; d1 = e1; d2 = e2; i0 = f0; i1 = f1; i2 = f2;
}

// Branchless strict-less insert (scan phase; ascending index => tiebreak ok).
__device__ __forceinline__ void ins_scan_(float dd, int n,
                                          float& d0, float& d1, float& d2,
                                          int& i0, int& i1, int& i2) {
    bool c0 = dd < d0;
    bool c1 = dd < d1;
    bool c2 = dd < d2;
    float n0 = fminf(dd, d0);
    float n1 = __builtin_amdgcn_fmed3f(dd, d0, d1);
    float n2 = __builtin_amdgcn_fmed3f(dd, d1, d2);
    int ta = c0 ? i0 : n;          // survivor of (d0 slot) displacement
    int j0 = c0 ? n  : i0;
    int j1 = c1 ? ta : i1;
    int tb = c1 ? i1 : n;
    int j2 = c2 ? tb : i2;
    d0 = n0; d1 = n1; d2 = n2;
    i0 = j0; i1 = j1; i2 = j2;
}

__global__ __launch_bounds__(256) void knn_kernel(
    const float* __restrict__ p1, const float* __restrict__ p2,
    int4* __restrict__ wsi, float4* __restrict__ wsw) {
#pragma clang fp contract(off)
    __shared__ float4 Q[N1_ / 2];   // 8 KB
    __shared__ float4 R[N1_ / 2];   // 8 KB

    const int tid   = threadIdx.x;
    const int b     = blockIdx.x >> 8;     // 256 query-tiles per batch
    const int mtile = blockIdx.x & 255;

    // Stage coarse points, pair-interleaved, with exact pre-doubling.
    for (int k = tid; k < N1_ / 2; k += 256) {
        const float* pa = &p1[((size_t)b * N1_ + 2 * k) * 3];
        float xa = pa[0], ya = pa[1], za = pa[2];
        float xb = pa[3], yb = pa[4], zb = pa[5];
        float sa = __fadd_rn(__fadd_rn(__fmul_rn(xa, xa), __fmul_rn(ya, ya)),
                             __fmul_rn(za, za));
        float sb = __fadd_rn(__fadd_rn(__fmul_rn(xb, xb), __fmul_rn(yb, yb)),
                             __fmul_rn(zb, zb));
        Q[k] = make_float4(xa + xa, xb + xb, ya + ya, yb + yb);
        R[k] = make_float4(za + za, zb + zb, sa, sb);
    }
    __syncthreads();

    const int q = tid >> 4;       // query within tile
    const int t = tid & 15;       // sub-thread within query
    const int m = mtile * QPB + q;

    const size_t pbase = ((size_t)b * N2_ + m) * 3;
    const float x2 = p2[pbase + 0];
    const float y2 = p2[pbase + 1];
    const float z2 = p2[pbase + 2];
    const float s2 = __fadd_rn(__fadd_rn(__fmul_rn(x2, x2), __fmul_rn(y2, y2)),
                               __fmul_rn(z2, z2));

    const vf2 x2v = {x2, x2};
    const vf2 y2v = {y2, y2};
    const vf2 z2v = {z2, z2};
    const vf2 s2v = {s2, s2};

    float d0 = FLT_MAX, d1 = FLT_MAX, d2 = FLT_MAX;
    int   i0 = INT_MAX, i1 = INT_MAX, i2 = INT_MAX;

    // 32 pair-iterations: candidates (2k, 2k+1), k = t + 16*j.
#pragma unroll 4
    for (int j = 0; j < N1_ / (2 * TPQ); ++j) {
        const int k = t + TPQ * j;
        float4 qv = Q[k];
        float4 rv = R[k];
        vf2 qx = {qv.x, qv.y};
        vf2 qy = {qv.z, qv.w};
        vf2 rz = {rv.x, rv.y};
        vf2 rs = {rv.z, rv.w};
        vf2 t1 = qx * x2v;          // v_pk_mul_f32 (RN, no fuse)
        vf2 t2 = qy * y2v;
        vf2 t3 = rz * z2v;
        vf2 dot2 = (t1 + t2) + t3;  // left-assoc, matches ref order
        vf2 dd = (s2v - dot2) + rs;
        ins_scan_(dd.x, 2 * k,     d0, d1, d2, i0, i1, i2);
        ins_scan_(dd.y, 2 * k + 1, d0, d1, d2, i0, i1, i2);
    }

    // Butterfly-merge the 16 partial lists (branchless, lexicographic).
    for (int mask = 1; mask < TPQ; mask <<= 1) {
        float pd0 = __shfl_xor(d0, mask, TPQ);
        float pd1 = __shfl_xor(d1, mask, TPQ);
        float pd2 = __shfl_xor(d2, mask, TPQ);
        int   pi0 = __shfl_xor(i0, mask, TPQ);
        int   pi1 = __shfl_xor(i1, mask, TPQ);
        int   pi2 = __shfl_xor(i2, mask, TPQ);
        ins_lex_(pd0, pi0, d0, d1, d2, i0, i1, i2);
        ins_lex_(pd1, pi1, d0, d1, d2, i0, i1, i2);
        ins_lex_(pd2, pi2, d0, d1, d2, i0, i1, i2);
    }

    if (t == 0) {
        float r0 = 1.0f / __fadd_rn(d0, 1e-8f);
        float r1 = 1.0f / __fadd_rn(d1, 1e-8f);
        float r2 = 1.0f / __fadd_rn(d2, 1e-8f);
        float s  = __fadd_rn(__fadd_rn(r0, r1), r2);
        const size_t o = (size_t)b * N2_ + m;
        wsi[o] = make_int4(i0, i1, i2, 0);
        wsw[o] = make_float4(r0 / s, r1 / s, r2 / s, 0.0f);
    }
}

// ---------------------------------------------------------------------------
// Kernel 2: gather + blend — UNCHANGED from round 2 (control variable).
// ---------------------------------------------------------------------------

__global__ __launch_bounds__(256) void blend_kernel(
    const float* __restrict__ x1, const int4* __restrict__ wsi,
    const float4* __restrict__ wsw, float* __restrict__ out) {
    __shared__ float L[4][N1_];   // 16 KB

    int bid = blockIdx.x;
    const int mhalf = bid & 1;
    const int ct    = (bid >> 1) & 63;   // 64 channel tiles of 4
    const int b     = bid >> 7;
    const int tid   = threadIdx.x;

    const float* src = x1 + ((size_t)b * C_ + ct * 4) * N1_;
    float4* Lv = reinterpret_cast<float4*>(&L[0][0]);
    const float4* Sv = reinterpret_cast<const float4*>(src);
#pragma unroll
    for (int j = 0; j < 4; ++j) Lv[tid + 256 * j] = Sv[tid + 256 * j];
    __syncthreads();

    const size_t wbase = (size_t)b * N2_;
    const size_t obase = ((size_t)b * C_ + (size_t)ct * 4) * N2_;

#pragma unroll
    for (int mb = 0; mb < 8; ++mb) {
        const int m = mhalf * 2048 + mb * 256 + tid;
        const int4   id = wsi[wbase + m];
        const float4 w  = wsw[wbase + m];
#pragma unroll
        for (int r = 0; r < 4; ++r) {
            float a  = L[r][id.x];
            float bb = L[r][id.y];
            float cc = L[r][id.z];
            float acc = __fadd_rn(__fadd_rn(__fmul_rn(a,  w.x),
                                            __fmul_rn(bb, w.y)),
                                  __fmul_rn(cc, w.z));
            __builtin_nontemporal_store(acc, &out[obase + (size_t)r * N2_ + m]);
        }
    }
}

extern "C" void kernel_launch(void* const* d_in, const int* in_sizes, int n_in,
                              void* d_out, int out_size, void* d_ws, size_t ws_size,
                              hipStream_t stream) {
    const float* p1 = (const float*)d_in[0];   // [B, N1, 3]
    const float* x1 = (const float*)d_in[1];   // [B, C, N1]
    const float* p2 = (const float*)d_in[2];   // [B, N2, 3]
    float* out = (float*)d_out;                // [B, C, N2]

    int4*   wsi = (int4*)d_ws;
    float4* wsw = (float4*)((char*)d_ws + (size_t)B_ * N2_ * sizeof(int4));

    knn_kernel<<<B_ * (N2_ / QPB), 256, 0, stream>>>(p1, p2, wsi, wsw);
    blend_kernel<<<B_ * (C_ / 4) * 2, 256, 0, stream>>>(x1, wsi, wsw, out);
}